// Round 2
// baseline (689.923 us; speedup 1.0000x reference)
//
#include <hip/hip_runtime.h>
#include <stdint.h>

#define B_ 1024
#define Q_ 65536
#define D_ 512
#define MT 128
#define NT 128
#define BK 64
#define NSPLIT 64
#define NCHUNK (Q_ / NSPLIT)   // 1024
#define NTILES (NCHUNK / NT)   // 8
#define KITERS (D_ / BK)       // 8
#define MAXCT (Q_ / NT)        // 512 worst-case sparse col-tiles

#define SCALE32 32.0f
#define C32 46.16624130844683f   // 32 * log2(e)

// ---- workspace layout (bytes) ----
// [0)      : rowv[2][B] f32 per-row loss values (8 KB)
// [16K)    : meta: int mcount, int nct
// [64K)    : mlist[Q] int compacted masked-row indices (256 KB)
// [512K)   : LSE partials f32 (Z of cos1), idx row*64+split (256 KB)
// [1 MB)   : top-10 partials f32, idx ((mat*B+row)*64+split)*10 (5.24 MB)
//            mat0 = top10(cos1, all cols); mat1 = top10(cos1, unmasked only)
// [7 MB)   : Zcorr partials f32, idx row*512+coltile (2 MB)
// [9 MB)   : sparse top-10 partials f32, idx (row*512+coltile)*10 (21 MB)
// [30 MB)  : p bf16 (1 MB)
// [32 MB)  : queue[0] bf16 (64 MB)
// [96 MB)  : w bf16, written only where mask!=0 (64 MB region)
#define WS_ROWV  0u
#define WS_META  16384u
#define WS_MLIST 65536u
#define WS_LSE   524288u
#define WS_TOPK  (1u * 1024u * 1024u)
#define WS_ZCORR (7u * 1024u * 1024u)
#define WS_TOPKS (9u * 1024u * 1024u)
#define WS_PBF   (30u * 1024u * 1024u)
#define WS_QBF0  (32u * 1024u * 1024u)
#define WS_WBF   (96u * 1024u * 1024u)

typedef __attribute__((ext_vector_type(8))) short short8;
typedef __attribute__((ext_vector_type(4))) short short4v;
typedef __attribute__((ext_vector_type(4))) float f32x4;

__device__ __forceinline__ unsigned short f2bf(float x) {
  union { float f; uint32_t u; } v; v.f = x;
  uint32_t r = v.u + 0x7fffu + ((v.u >> 16) & 1u);   // RNE
  return (unsigned short)(r >> 16);
}

__device__ __forceinline__ float bf2f(short u) {
  union { uint32_t i; float f; } v;
  v.i = ((uint32_t)(unsigned short)u) << 16;
  return v.f;
}

__device__ __forceinline__ void async16(void* lds, const void* g) {
  void* gg = (void*)g;
  __builtin_amdgcn_global_load_lds(
      (__attribute__((address_space(1))) unsigned int*)gg,
      (__attribute__((address_space(3))) unsigned int*)lds,
      16, 0, 0);
}

__device__ __forceinline__ void tkins(float v,
    float& t0, float& t1, float& t2, float& t3, float& t4,
    float& t5, float& t6, float& t7, float& t8, float& t9) {
  if (v > t9) {
    t9 = (v > t8) ? t8 : v;
    t8 = (v > t8) ? ((v > t7) ? t7 : v) : t8;
    t7 = (v > t7) ? ((v > t6) ? t6 : v) : t7;
    t6 = (v > t6) ? ((v > t5) ? t5 : v) : t6;
    t5 = (v > t5) ? ((v > t4) ? t4 : v) : t5;
    t4 = (v > t4) ? ((v > t3) ? t3 : v) : t4;
    t3 = (v > t3) ? ((v > t2) ? t2 : v) : t3;
    t2 = (v > t2) ? ((v > t1) ? t1 : v) : t2;
    t1 = (v > t1) ? ((v > t0) ? t0 : v) : t1;
    t0 = (v > t0) ? v : t0;
  }
}

#define TKA(v, a) tkins((v), a[0], a[1], a[2], a[3], a[4], a[5], a[6], a[7], a[8], a[9])

// deterministic ordered compaction of masked queue rows (single block)
__global__ __launch_bounds__(1024, 1) void compact_scan(
    const float* __restrict__ mask, char* __restrict__ ws) {
  __shared__ int wsum[16];
  __shared__ int carry;
  const int tid = threadIdx.x;
  const int lane = tid & 63, wv = tid >> 6;
  int* mlist = (int*)(ws + WS_MLIST);
  if (tid == 0) carry = 0;
  __syncthreads();
  for (int c = 0; c < Q_ / 1024; ++c) {
    const int r = c * 1024 + tid;
    const bool m = mask[r] != 0.0f;
    unsigned long long b = __ballot(m);
    const int lpre = __popcll(b & ((1ull << lane) - 1ull));
    if (lane == 0) wsum[wv] = __popcll(b);
    __syncthreads();
    int wbase = 0;
#pragma unroll
    for (int i = 0; i < 16; ++i) wbase += (i < wv) ? wsum[i] : 0;
    int ctot = 0;
#pragma unroll
    for (int i = 0; i < 16; ++i) ctot += wsum[i];
    if (m) mlist[carry + wbase + lpre] = r;
    __syncthreads();
    if (tid == 0) carry += ctot;
    __syncthreads();
  }
  if (tid == 0) {
    int* meta = (int*)(ws + WS_META);
    meta[0] = carry;                      // mcount
    meta[1] = (carry + NT - 1) / NT;      // nct
  }
}

// fused converter: queue fp32 -> qbf0 always; wbf only where mask!=0; p -> pbf
__global__ void cvt_all(const float* __restrict__ q, const float* __restrict__ p,
                        const float* __restrict__ mask,
                        unsigned short* __restrict__ qbf0,
                        unsigned short* __restrict__ wbf,
                        unsigned short* __restrict__ pbf) {
  const int wv = threadIdx.x >> 6;
  const int lane = threadIdx.x & 63;
  const int b = blockIdx.x;
  if (b < Q_ / 4) {
    const int row = b * 4 + wv;
    const float* q0r = q + (size_t)row * D_ + lane * 8;
    float4 a = ((const float4*)q0r)[0];
    float4 bb = ((const float4*)q0r)[1];
    short8 o;
    o[0] = (short)f2bf(a.x); o[1] = (short)f2bf(a.y);
    o[2] = (short)f2bf(a.z); o[3] = (short)f2bf(a.w);
    o[4] = (short)f2bf(bb.x); o[5] = (short)f2bf(bb.y);
    o[6] = (short)f2bf(bb.z); o[7] = (short)f2bf(bb.w);
    *(short8*)(qbf0 + (size_t)row * D_ + lane * 8) = o;
    float m = mask[row];
    if (m != 0.0f) {      // wave-uniform; ~10% of rows
      const float* q1r = q0r + (size_t)Q_ * D_;
      float4 c = ((const float4*)q1r)[0];
      float4 d = ((const float4*)q1r)[1];
      a.x = fmaf(m, c.x - a.x, a.x); a.y = fmaf(m, c.y - a.y, a.y);
      a.z = fmaf(m, c.z - a.z, a.z); a.w = fmaf(m, c.w - a.w, a.w);
      bb.x = fmaf(m, d.x - bb.x, bb.x); bb.y = fmaf(m, d.y - bb.y, bb.y);
      bb.z = fmaf(m, d.z - bb.z, bb.z); bb.w = fmaf(m, d.w - bb.w, bb.w);
      o[0] = (short)f2bf(a.x); o[1] = (short)f2bf(a.y);
      o[2] = (short)f2bf(a.z); o[3] = (short)f2bf(a.w);
      o[4] = (short)f2bf(bb.x); o[5] = (short)f2bf(bb.y);
      o[6] = (short)f2bf(bb.z); o[7] = (short)f2bf(bb.w);
      *(short8*)(wbf + (size_t)row * D_ + lane * 8) = o;
    }
  } else {
    const int row = (b - Q_ / 4) * 4 + wv;
    const float* pr = p + (size_t)row * D_ + lane * 8;
    float4 a = ((const float4*)pr)[0];
    float4 bb = ((const float4*)pr)[1];
    short8 o;
    o[0] = (short)f2bf(a.x); o[1] = (short)f2bf(a.y);
    o[2] = (short)f2bf(a.z); o[3] = (short)f2bf(a.w);
    o[4] = (short)f2bf(bb.x); o[5] = (short)f2bf(bb.y);
    o[6] = (short)f2bf(bb.z); o[7] = (short)f2bf(bb.w);
    *(short8*)(pbf + (size_t)row * D_ + lane * 8) = o;
  }
}

// grid (64, 8): x=split -> XCD=split%8, 2-3 blocks/CU. SINGLE-B GEMM (cos1 only).
// Z: register accumulation across nt, one shuffle-reduce at end.
// Top-10: mat0 = cos1 all cols; mat1 = cos1 with masked cols -> -inf.
__global__ __launch_bounds__(256, 2) void fused_gemm_partial(
    const unsigned short* __restrict__ pbf,
    const unsigned short* __restrict__ qbf0,
    const float* __restrict__ maskp,
    const int* __restrict__ label,
    char* __restrict__ ws) {
  __shared__ __align__(16) unsigned char smem[32768];   // SA 16K | SB 16K
  __shared__ float maskb[NT];
  __shared__ float zacc[MT][2];
  __shared__ int olist[MT];
  __shared__ int rowmap[MT];
  __shared__ int sh_ocount;

  const int tid = threadIdx.x;
  const int split = blockIdx.x;       // 0..63
  const int mblk = blockIdx.y;        // 0..7
  const int lane = tid & 63;
  const int wv = tid >> 6;
  const int wr = wv >> 1;
  const int wc = wv & 1;
  const int lr = lane & 15;
  const int lg = lane >> 4;

  if (tid == 0) sh_ocount = 0;
  if (tid < MT) rowmap[tid] = -1;
  __syncthreads();
  if (tid < MT) {
    if (label[mblk * MT + tid] == -1) {
      int k = atomicAdd(&sh_ocount, 1);
      olist[k] = tid;
    }
  }
  __syncthreads();
  const int noc = sh_ocount;
  if (tid < noc) rowmap[olist[tid]] = tid;
  __syncthreads();
  const int nchunks = (noc + 31) >> 5;

  const int srow = lane >> 3;
  const int sc16 = (lane & 7) ^ srow;
  const size_t g_lane_off = (size_t)srow * D_ + sc16 * 8;

  float T[10];
#pragma unroll
  for (int i = 0; i < 10; ++i) T[i] = -1e30f;
  float zreg[4][4];
#pragma unroll
  for (int i = 0; i < 4; ++i)
#pragma unroll
    for (int k = 0; k < 4; ++k) zreg[i][k] = 0.0f;

  for (int nt = 0; nt < NTILES; ++nt) {
    const int nbase = split * NCHUNK + nt * NT;
    if (tid < NT) maskb[tid] = maskp[nbase + tid];
    __syncthreads();

    f32x4 acc[4][4];
#pragma unroll
    for (int i = 0; i < 4; ++i)
#pragma unroll
      for (int j = 0; j < 4; ++j) {
        f32x4 z = {0.0f, 0.0f, 0.0f, 0.0f};
        acc[i][j] = z;
      }

    const unsigned short* abase[4];
    const unsigned short* bbase[4];
#pragma unroll
    for (int t = 0; t < 4; ++t) {
      const int slot = wv * 4 + t;
      abase[t] = pbf + ((size_t)mblk * MT + slot * 8) * D_ + g_lane_off;
      bbase[t] = qbf0 + ((size_t)nbase + slot * 8) * D_ + g_lane_off;
    }

    for (int kk = 0; kk < KITERS; ++kk) {
      const size_t kcol = (size_t)kk * BK;
#pragma unroll
      for (int t = 0; t < 4; ++t) {
        const int slot = wv * 4 + t;
        async16(smem + slot * 1024, abase[t] + kcol);
        async16(smem + 16384 + slot * 1024, bbase[t] + kcol);
      }
      __syncthreads();

#pragma unroll
      for (int s = 0; s < 2; ++s) {
        const int xs = ((s * 4 + lg) ^ (lr & 7)) * 16;
        short8 af[4], bf[4];
#pragma unroll
        for (int i = 0; i < 4; ++i)
          af[i] = *(const short8*)(smem + (wr * 64 + i * 16 + lr) * 128 + xs);
#pragma unroll
        for (int j = 0; j < 4; ++j)
          bf[j] = *(const short8*)(smem + 16384 + (wc * 64 + j * 16 + lr) * 128 + xs);
#pragma unroll
        for (int i = 0; i < 4; ++i)
#pragma unroll
          for (int j = 0; j < 4; ++j)
            acc[i][j] = __builtin_amdgcn_mfma_f32_16x16x32_bf16(af[i], bf[j], acc[i][j], 0, 0, 0);
      }
      __syncthreads();
    }

    // ---- Z: exps into registers, no per-nt shuffles ----
#pragma unroll
    for (int i = 0; i < 4; ++i)
#pragma unroll
      for (int k = 0; k < 4; ++k) {
        float a0 = 0.0f;
#pragma unroll
        for (int j = 0; j < 4; ++j)
          a0 += __builtin_amdgcn_exp2f(fmaf(acc[i][j][k], C32, -C32));
        zreg[i][k] += a0;
      }

    // per-thread mask flags for the 4 cols this thread owns per j
    bool mflag[4];
#pragma unroll
    for (int j = 0; j < 4; ++j) mflag[j] = maskb[wc * 64 + j * 16 + lr] != 0.0f;

    // ---- top-10: LDS compact (mat0=cos1, mat1=cos1 masked->-inf) -> scans ----
    for (int c = 0; c < nchunks; ++c) {
      unsigned short* cp = (unsigned short*)smem;   // aliases SA+SB (16 KB used)
#pragma unroll
      for (int i = 0; i < 4; ++i)
#pragma unroll
        for (int k = 0; k < 4; ++k) {
          const int r = wr * 64 + i * 16 + lg * 4 + k;
          const int o = rowmap[r];
          const int ol = o - c * 32;
          if (o >= 0 && ol >= 0 && ol < 32) {
#pragma unroll
            for (int j = 0; j < 4; ++j) {
              const int col = wc * 64 + j * 16 + lr;
              const unsigned short v = f2bf(acc[i][j][k]);
              cp[ol * 128 + col] = v;
              cp[(32 + ol) * 128 + col] = mflag[j] ? (unsigned short)0xFF80 : v;
            }
          }
        }
      __syncthreads();

      {
        float tl[10];
#pragma unroll
        for (int r = 0; r < 10; ++r) tl[r] = -1e30f;
        const int pair = tid >> 2;      // 0..63: (orow, mat)
        const int q4 = tid & 3;
        const int orow = pair >> 1, mat = pair & 1;
        const int o = c * 32 + orow;
        if (o < noc) {
          const unsigned short* rp = cp + (mat * 32 + orow) * 128 + q4 * 32;
#pragma unroll
          for (int cc = 0; cc < 8; ++cc) {
            short4v v = *(const short4v*)(rp + cc * 4);
            TKA(bf2f(v.x), tl); TKA(bf2f(v.y), tl);
            TKA(bf2f(v.z), tl); TKA(bf2f(v.w), tl);
          }
          float ot[10];
#pragma unroll
          for (int r = 0; r < 10; ++r) ot[r] = __shfl_xor(tl[r], 1, 64);
#pragma unroll
          for (int r = 0; r < 10; ++r) TKA(ot[r], tl);
#pragma unroll
          for (int r = 0; r < 10; ++r) ot[r] = __shfl_xor(tl[r], 2, 64);
#pragma unroll
          for (int r = 0; r < 10; ++r) TKA(ot[r], tl);
          if (q4 == 0) {
            if (c == 0) {
#pragma unroll
              for (int r = 0; r < 10; ++r) TKA(tl[r], T);
            } else {
              float* slot = (float*)(ws + WS_TOPK) +
                  ((size_t)(mat * B_ + mblk * MT + olist[o]) * NSPLIT + split) * 10;
              if (nt == 0) {
#pragma unroll
                for (int r = 0; r < 10; ++r) slot[r] = tl[r];
              } else {
                float cur[10];
#pragma unroll
                for (int r = 0; r < 10; ++r) cur[r] = slot[r];
#pragma unroll
                for (int r = 0; r < 10; ++r) TKA(tl[r], cur);
#pragma unroll
                for (int r = 0; r < 10; ++r) slot[r] = cur[r];
              }
            }
          }
        }
      }
      __syncthreads();
    }
  }

  // ---- Z final shuffle-reduce + write ----
#pragma unroll
  for (int i = 0; i < 4; ++i)
#pragma unroll
    for (int k = 0; k < 4; ++k) {
      float v = zreg[i][k];
#pragma unroll
      for (int m = 1; m < 16; m <<= 1) v += __shfl_xor(v, m, 64);
      if (lr == 0) zacc[wr * 64 + i * 16 + lg * 4 + k][wc] = v;
    }
  __syncthreads();
  if (tid < MT) {
    ((float*)(ws + WS_LSE))[(size_t)(mblk * MT + tid) * NSPLIT + split] =
        zacc[tid][0] + zacc[tid][1];
  }
  {
    const int pair = tid >> 2;
    const int q4 = tid & 3;
    const int orow = pair >> 1, mat = pair & 1;
    if (q4 == 0 && orow < noc && orow < 32) {
      float* slot = (float*)(ws + WS_TOPK) +
          ((size_t)(mat * B_ + mblk * MT + olist[orow]) * NSPLIT + split) * 10;
#pragma unroll
      for (int r = 0; r < 10; ++r) slot[r] = T[r];
    }
  }
}

// dual-GEMM over COMPACTED masked columns only (~10% of Q). B rows gathered via
// per-lane global_load_lds source addresses. Writes Zcorr partial per (row,coltile)
// and top-10(cos2) lists for outlier rows.
__global__ __launch_bounds__(256, 2) void sparse_gemm(
    const unsigned short* __restrict__ pbf,
    const unsigned short* __restrict__ qbf0,
    const unsigned short* __restrict__ wbf,
    const int* __restrict__ label,
    char* __restrict__ ws) {
  const int* meta = (const int*)(ws + WS_META);
  const int mcount = meta[0];
  const int ct = blockIdx.x;            // coltile
  if (ct * NT >= mcount) return;
  const int mblk = blockIdx.y;

  __shared__ __align__(16) unsigned char smem[49152]; // SA|SB0|SB1 16K each
  __shared__ int mrow[NT];
  __shared__ float zsum[MT][2];
  __shared__ int olist[MT];
  __shared__ int rowmap[MT];
  __shared__ int sh_ocount;

  const int tid = threadIdx.x;
  const int lane = tid & 63;
  const int wv = tid >> 6;
  const int wr = wv >> 1;
  const int wc = wv & 1;
  const int lr = lane & 15;
  const int lg = lane >> 4;

  if (tid == 0) sh_ocount = 0;
  if (tid < MT) rowmap[tid] = -1;
  if (tid < NT) {
    const int ci = ct * NT + tid;
    mrow[tid] = (ci < mcount) ? ((const int*)(ws + WS_MLIST))[ci] : -1;
  }
  __syncthreads();
  if (tid < MT) {
    if (label[mblk * MT + tid] == -1) {
      int k = atomicAdd(&sh_ocount, 1);
      olist[k] = tid;
    }
  }
  __syncthreads();
  const int noc = sh_ocount;
  if (tid < noc) rowmap[olist[tid]] = tid;
  __syncthreads();
  const int nchunks = (noc + 31) >> 5;

  const int srow = lane >> 3;
  const int sc16 = (lane & 7) ^ srow;
  const size_t g_lane_off = (size_t)srow * D_ + sc16 * 8;
  const size_t c_lane_off = (size_t)sc16 * 8;

  const unsigned short* abase[4];
  size_t brow_off[4];
#pragma unroll
  for (int t = 0; t < 4; ++t) {
    const int slot = wv * 4 + t;
    abase[t] = pbf + ((size_t)mblk * MT + slot * 8) * D_ + g_lane_off;
    int r = mrow[slot * 8 + srow];
    brow_off[t] = (size_t)(r < 0 ? 0 : r) * D_ + c_lane_off;
  }

  f32x4 acc0[4][4], acc1[4][4];
#pragma unroll
  for (int i = 0; i < 4; ++i)
#pragma unroll
    for (int j = 0; j < 4; ++j) {
      f32x4 z = {0.0f, 0.0f, 0.0f, 0.0f};
      acc0[i][j] = z;
      acc1[i][j] = z;
    }

  for (int kk = 0; kk < KITERS; ++kk) {
    const size_t kcol = (size_t)kk * BK;
#pragma unroll
    for (int t = 0; t < 4; ++t) {
      const int slot = wv * 4 + t;
      async16(smem + slot * 1024, abase[t] + kcol);
      async16(smem + 16384 + slot * 1024, qbf0 + brow_off[t] + kcol);
      async16(smem + 32768 + slot * 1024, wbf + brow_off[t] + kcol);
    }
    __syncthreads();

#pragma unroll
    for (int s = 0; s < 2; ++s) {
      const int xs = ((s * 4 + lg) ^ (lr & 7)) * 16;
      short8 af[4], b0[4], b1[4];
#pragma unroll
      for (int i = 0; i < 4; ++i)
        af[i] = *(const short8*)(smem + (wr * 64 + i * 16 + lr) * 128 + xs);
#pragma unroll
      for (int j = 0; j < 4; ++j)
        b0[j] = *(const short8*)(smem + 16384 + (wc * 64 + j * 16 + lr) * 128 + xs);
#pragma unroll
      for (int j = 0; j < 4; ++j)
        b1[j] = *(const short8*)(smem + 32768 + (wc * 64 + j * 16 + lr) * 128 + xs);
#pragma unroll
      for (int i = 0; i < 4; ++i)
#pragma unroll
        for (int j = 0; j < 4; ++j) {
          acc0[i][j] = __builtin_amdgcn_mfma_f32_16x16x32_bf16(af[i], b0[j], acc0[i][j], 0, 0, 0);
          acc1[i][j] = __builtin_amdgcn_mfma_f32_16x16x32_bf16(af[i], b1[j], acc1[i][j], 0, 0, 0);
        }
    }
    __syncthreads();
  }

  // ---- Zcorr = sum over valid cols of exp(cos2)-exp(cos1) ----
#pragma unroll
  for (int i = 0; i < 4; ++i)
#pragma unroll
    for (int k = 0; k < 4; ++k) {
      float d = 0.0f;
#pragma unroll
      for (int j = 0; j < 4; ++j) {
        const int col = wc * 64 + j * 16 + lr;
        const bool valid = (ct * NT + col) < mcount;
        float e = __builtin_amdgcn_exp2f(fmaf(acc1[i][j][k], C32, -C32)) -
                  __builtin_amdgcn_exp2f(fmaf(acc0[i][j][k], C32, -C32));
        d += valid ? e : 0.0f;
      }
#pragma unroll
      for (int m = 1; m < 16; m <<= 1) d += __shfl_xor(d, m, 64);
      if (lr == 0) zsum[wr * 64 + i * 16 + lg * 4 + k][wc] = d;
    }
  __syncthreads();
  if (tid < MT) {
    ((float*)(ws + WS_ZCORR))[(size_t)(mblk * MT + tid) * MAXCT + ct] =
        zsum[tid][0] + zsum[tid][1];
  }

  // ---- top-10 of cos2 over this coltile, outlier rows only ----
  for (int c = 0; c < nchunks; ++c) {
    unsigned short* cp = (unsigned short*)smem;   // 8 KB
#pragma unroll
    for (int i = 0; i < 4; ++i)
#pragma unroll
      for (int k = 0; k < 4; ++k) {
        const int r = wr * 64 + i * 16 + lg * 4 + k;
        const int o = rowmap[r];
        const int ol = o - c * 32;
        if (o >= 0 && ol >= 0 && ol < 32) {
#pragma unroll
          for (int j = 0; j < 4; ++j) {
            const int col = wc * 64 + j * 16 + lr;
            const bool valid = (ct * NT + col) < mcount;
            cp[ol * 128 + col] = valid ? f2bf(acc1[i][j][k]) : (unsigned short)0xFF80;
          }
        }
      }
    __syncthreads();

    {
      float tl[10];
#pragma unroll
      for (int r = 0; r < 10; ++r) tl[r] = -1e30f;
      const int orow = tid >> 3;        // 0..31
      const int q8 = tid & 7;
      const int o = c * 32 + orow;
      if (o < noc) {
        const unsigned short* rp = cp + orow * 128 + q8 * 16;
#pragma unroll
        for (int cc = 0; cc < 4; ++cc) {
          short4v v = *(const short4v*)(rp + cc * 4);
          TKA(bf2f(v.x), tl); TKA(bf2f(v.y), tl);
          TKA(bf2f(v.z), tl); TKA(bf2f(v.w), tl);
        }
        float ot[10];
#pragma unroll
        for (int r = 0; r < 10; ++r) ot[r] = __shfl_xor(tl[r], 1, 64);
#pragma unroll
        for (int r = 0; r < 10; ++r) TKA(ot[r], tl);
#pragma unroll
        for (int r = 0; r < 10; ++r) ot[r] = __shfl_xor(tl[r], 2, 64);
#pragma unroll
        for (int r = 0; r < 10; ++r) TKA(ot[r], tl);
#pragma unroll
        for (int r = 0; r < 10; ++r) ot[r] = __shfl_xor(tl[r], 4, 64);
#pragma unroll
        for (int r = 0; r < 10; ++r) TKA(ot[r], tl);
        if (q8 == 0) {
          float* slot = (float*)(ws + WS_TOPKS) +
              ((size_t)(mblk * MT + olist[o]) * MAXCT + ct) * 10;
#pragma unroll
          for (int r = 0; r < 10; ++r) slot[r] = tl[r];
        }
      }
    }
    __syncthreads();
  }
}

// per-row: no global atomics — each row writes rowv[l*B+row]; reduce_final sums.
__global__ void finalize_rows(
    const float* __restrict__ p, const float* __restrict__ queue,
    const float* __restrict__ maskp, const int* __restrict__ label,
    char* __restrict__ ws, float* __restrict__ out) {
  const int row = blockIdx.x;
  const int l = threadIdx.x >> 6;     // 0: cos1 loss, 1: cos2 loss
  const int lane = threadIdx.x & 63;
  const int lab = label[row];
  float* rowv = (float*)(ws + WS_ROWV);
  const int nct = ((const int*)(ws + WS_META))[1];

  if (lab != -1) {
    // ---- Z1 = sum of 64 split partials; Z2 = Z1 + sum of Zcorr tiles ----
    const float* lsep = (const float*)(ws + WS_LSE) + (size_t)row * NSPLIT;
    float z = lsep[lane];
#pragma unroll
    for (int o = 1; o < 64; o <<= 1) z += __shfl_xor(z, o, 64);
    if (l == 1) {
      const float* zcp = (const float*)(ws + WS_ZCORR) + (size_t)row * MAXCT;
      float zc = 0.0f;
      for (int t = lane; t < nct; t += 64) zc += zcp[t];
#pragma unroll
      for (int o = 1; o < 64; o <<= 1) zc += __shfl_xor(zc, o, 64);
      z += zc;
    }

    // ---- exact fp32 gt dot(s) ----
    const float* prow = p + (size_t)row * D_;
    const float* q0r = queue + (size_t)lab * D_;
    const float* q1r = queue + ((size_t)Q_ + (size_t)lab) * D_;
    int c = lane * 8;
    float4 a0 = *(const float4*)(prow + c);
    float4 a1 = *(const float4*)(prow + c + 4);
    float4 b0 = *(const float4*)(q0r + c);
    float4 b1 = *(const float4*)(q0r + c + 4);
    float d0 = a0.x * b0.x + a0.y * b0.y + a0.z * b0.z + a0.w * b0.w
             + a1.x * b1.x + a1.y * b1.y + a1.z * b1.z + a1.w * b1.w;
    float d1 = 0.0f;
    if (l == 1) {
      float4 c0 = *(const float4*)(q1r + c);
      float4 c1 = *(const float4*)(q1r + c + 4);
      d1 = a0.x * c0.x + a0.y * c0.y + a0.z * c0.z + a0.w * c0.w
         + a1.x * c1.x + a1.y * c1.y + a1.z * c1.z + a1.w * c1.w;
    }
#pragma unroll
    for (int o = 1; o < 64; o <<= 1) {
      d0 += __shfl_xor(d0, o, 64);
      d1 += __shfl_xor(d1, o, 64);
    }
    float gt;
    if (l == 0) gt = d0;
    else { float m = maskp[lab]; gt = fmaf(m, d1 - d0, d0); }

    if (lane == 0) {
      float e1 = __builtin_amdgcn_exp2f(fmaf(gt, C32, -C32));
      float e2 = __builtin_amdgcn_exp2f(fmaf(gt - 0.4f, C32, -C32));
      float Zc = z - e1 + e2;
      float ce = 32.0f + __logf(Zc) - (gt - 0.4f) * SCALE32;
      rowv[l * B_ + row] = ce;
    }
  } else {
    // ---- merge lists: 64 split lists (+ sparse coltile lists for l==1) ----
    float tl[10];
    const float* tp = (const float*)(ws + WS_TOPK) +
                      ((size_t)l * B_ + row) * NSPLIT * 10 + (size_t)lane * 10;
#pragma unroll
    for (int r = 0; r < 10; ++r) tl[r] = tp[r];
    if (l == 1) {
      const float* sp = (const float*)(ws + WS_TOPKS) + (size_t)row * MAXCT * 10;
      for (int t = lane; t < nct; t += 64) {
        const float* spp = sp + (size_t)t * 10;
#pragma unroll
        for (int r = 0; r < 10; ++r) TKA(spp[r], tl);
      }
    }
    float ssum = 0.0f;
#pragma unroll
    for (int r10 = 0; r10 < 10; ++r10) {
      float v = tl[0];
      int idx = lane;
#pragma unroll
      for (int o = 1; o < 64; o <<= 1) {
        float ov = __shfl_xor(v, o, 64);
        int oi = __shfl_xor(idx, o, 64);
        bool take = (ov > v) || (ov == v && oi < idx);
        v = take ? ov : v;
        idx = take ? oi : idx;
      }
      ssum += fmaxf(v, 0.0f);
      if (idx == lane) {
#pragma unroll
        for (int q = 0; q < 9; ++q) tl[q] = tl[q + 1];
        tl[9] = -1e30f;
      }
    }
    if (lane == 0) rowv[l * B_ + row] = ssum * 0.1f;
  }
}

// single-block deterministic reduction
__global__ void reduce_final(const int* __restrict__ label,
                             const char* __restrict__ ws,
                             float* __restrict__ out) {
  __shared__ float sce[4], sng[4];
  __shared__ int snp[4], snn[4];
  const int tid = threadIdx.x;        // 256 threads
  const float* rowv = (const float*)(ws + WS_ROWV);
  float ce = 0.0f, ng = 0.0f;
  int np = 0, nn = 0;
  for (int r = tid; r < B_; r += 256) {
    float v = rowv[r] + rowv[B_ + r];
    if (label[r] != -1) { ce += v; ++np; }
    else { ng += v; ++nn; }
  }
#pragma unroll
  for (int o = 1; o < 64; o <<= 1) {
    ce += __shfl_xor(ce, o, 64);
    ng += __shfl_xor(ng, o, 64);
    np += __shfl_xor(np, o, 64);
    nn += __shfl_xor(nn, o, 64);
  }
  const int wv = tid >> 6, lane = tid & 63;
  if (lane == 0) { sce[wv] = ce; sng[wv] = ng; snp[wv] = np; snn[wv] = nn; }
  __syncthreads();
  if (tid == 0) {
    float c = 0.0f, g = 0.0f; int pp = 0, n = 0;
#pragma unroll
    for (int i = 0; i < 4; ++i) { c += sce[i]; g += sng[i]; pp += snp[i]; n += snn[i]; }
    float loss = 0.0f;
    if (pp > 0) loss += c / (float)pp;
    if (n > 0) loss += g / (float)n;
    out[0] = loss;
  }
}

extern "C" void kernel_launch(void* const* d_in, const int* in_sizes, int n_in,
                              void* d_out, int out_size, void* d_ws, size_t ws_size,
                              hipStream_t stream) {
  const float* p     = (const float*)d_in[0];
  const float* queue = (const float*)d_in[1];
  const float* maskp = (const float*)d_in[2];
  const int*   label = (const int*)d_in[3];
  float* out = (float*)d_out;
  char* ws = (char*)d_ws;

  unsigned short* pbf  = (unsigned short*)(ws + WS_PBF);
  unsigned short* qbf0 = (unsigned short*)(ws + WS_QBF0);
  unsigned short* wbf  = (unsigned short*)(ws + WS_WBF);

  compact_scan<<<1, 1024, 0, stream>>>(maskp, ws);
  cvt_all<<<Q_ / 4 + B_ / 4, 256, 0, stream>>>(queue, p, maskp, qbf0, wbf, pbf);

  dim3 g1(NSPLIT, B_ / MT);   // (64, 8): x=split -> XCD=split%8
  fused_gemm_partial<<<g1, 256, 0, stream>>>(pbf, qbf0, maskp, label, ws);

  dim3 g2(MAXCT, B_ / MT);    // blocks beyond nct exit immediately
  sparse_gemm<<<g2, 256, 0, stream>>>(pbf, qbf0, wbf, label, ws);

  finalize_rows<<<B_, 128, 0, stream>>>(p, queue, maskp, label, ws, out);
  reduce_final<<<1, 256, 0, stream>>>(label, ws, out);
}

// Round 3
// 607.614 us; speedup vs baseline: 1.1355x; 1.1355x over previous
//
#include <hip/hip_runtime.h>
#include <stdint.h>

#define B_ 1024
#define Q_ 65536
#define D_ 512
#define MT 128
#define NT 128
#define NSPLIT 64
#define NCHUNK (Q_ / NSPLIT)   // 1024
#define NTILES (NCHUNK / NT)   // 8
#define KIT2 (D_ / 32)         // 16 K-steps of 32

#define SCALE32 32.0f
#define C32 46.16624130844683f   // 32 * log2(e)

// ---- workspace layout (bytes) ----
// [0,8K)   : rowv[2][B] f32 per-row loss values
// [16K)    : LSE partials float2(Z_mat0, Z_mat1), idx row*64+split  (512 KB)
// [1 MB)   : top-10 partials, idx ((mat*B+row)*64+split)*10         (5.24 MB)
// [8 MB)   : p bf16 (1 MB)
// [12 MB)  : queue[0] bf16 (64 MB)
// [76 MB)  : w = m*q1+(1-m)*q0 bf16, written only where mask!=0 (64 MB region)
#define WS_ROWV 0
#define WS_LSE  16384
#define WS_TOPK (1u * 1024u * 1024u)
#define WS_PBF  (8u * 1024u * 1024u)
#define WS_QBF0 (12u * 1024u * 1024u)
#define WS_WBF  (76u * 1024u * 1024u)

// ---- LDS: 3 pipeline buffers x 24KB (A 8K | B0 8K | B1 8K). BK=32, 64B rows.
// Swizzle: phys slot16 = lg ^ (row&3) ^ ((row>>2)&1)  (2 lanes/bank = free).
// Depth-2: counted vmcnt(6) + raw s_barrier; 6 loads in flight across barriers.
// topk compact (16 KB) aliases buf0 after the K-loop's trailing __syncthreads.
#define SBUF3 24576
#define SB0_OFF3 8192
#define SB1_OFF3 16384

typedef __attribute__((ext_vector_type(8))) short short8;
typedef __attribute__((ext_vector_type(4))) short short4v;
typedef __attribute__((ext_vector_type(4))) float f32x4;

__device__ __forceinline__ unsigned short f2bf(float x) {
  union { float f; uint32_t u; } v; v.f = x;
  uint32_t r = v.u + 0x7fffu + ((v.u >> 16) & 1u);   // RNE
  return (unsigned short)(r >> 16);
}

__device__ __forceinline__ float bf2f(short u) {
  union { uint32_t i; float f; } v;
  v.i = ((uint32_t)(unsigned short)u) << 16;
  return v.f;
}

__device__ __forceinline__ void async16(void* lds, const void* g) {
  void* gg = (void*)g;
  __builtin_amdgcn_global_load_lds(
      (__attribute__((address_space(1))) unsigned int*)gg,
      (__attribute__((address_space(3))) unsigned int*)lds,
      16, 0, 0);
}

__device__ __forceinline__ void tkins(float v,
    float& t0, float& t1, float& t2, float& t3, float& t4,
    float& t5, float& t6, float& t7, float& t8, float& t9) {
  if (v > t9) {
    t9 = (v > t8) ? t8 : v;
    t8 = (v > t8) ? ((v > t7) ? t7 : v) : t8;
    t7 = (v > t7) ? ((v > t6) ? t6 : v) : t7;
    t6 = (v > t6) ? ((v > t5) ? t5 : v) : t6;
    t5 = (v > t5) ? ((v > t4) ? t4 : v) : t5;
    t4 = (v > t4) ? ((v > t3) ? t3 : v) : t4;
    t3 = (v > t3) ? ((v > t2) ? t2 : v) : t3;
    t2 = (v > t2) ? ((v > t1) ? t1 : v) : t2;
    t1 = (v > t1) ? ((v > t0) ? t0 : v) : t1;
    t0 = (v > t0) ? v : t0;
  }
}

#define TKA(v, a) tkins((v), a[0], a[1], a[2], a[3], a[4], a[5], a[6], a[7], a[8], a[9])

// fused converter: queue fp32 -> qbf0 always; wbf only where mask!=0; p -> pbf
__global__ void cvt_all(const float* __restrict__ q, const float* __restrict__ p,
                        const float* __restrict__ mask,
                        unsigned short* __restrict__ qbf0,
                        unsigned short* __restrict__ wbf,
                        unsigned short* __restrict__ pbf) {
  const int wv = threadIdx.x >> 6;
  const int lane = threadIdx.x & 63;
  const int b = blockIdx.x;
  if (b < Q_ / 4) {
    const int row = b * 4 + wv;
    const float* q0r = q + (size_t)row * D_ + lane * 8;
    float4 a = ((const float4*)q0r)[0];
    float4 bb = ((const float4*)q0r)[1];
    short8 o;
    o[0] = (short)f2bf(a.x); o[1] = (short)f2bf(a.y);
    o[2] = (short)f2bf(a.z); o[3] = (short)f2bf(a.w);
    o[4] = (short)f2bf(bb.x); o[5] = (short)f2bf(bb.y);
    o[6] = (short)f2bf(bb.z); o[7] = (short)f2bf(bb.w);
    *(short8*)(qbf0 + (size_t)row * D_ + lane * 8) = o;
    float m = mask[row];
    if (m != 0.0f) {      // wave-uniform; ~10% of rows
      const float* q1r = q0r + (size_t)Q_ * D_;
      float4 c = ((const float4*)q1r)[0];
      float4 d = ((const float4*)q1r)[1];
      a.x = fmaf(m, c.x - a.x, a.x); a.y = fmaf(m, c.y - a.y, a.y);
      a.z = fmaf(m, c.z - a.z, a.z); a.w = fmaf(m, c.w - a.w, a.w);
      bb.x = fmaf(m, d.x - bb.x, bb.x); bb.y = fmaf(m, d.y - bb.y, bb.y);
      bb.z = fmaf(m, d.z - bb.z, bb.z); bb.w = fmaf(m, d.w - bb.w, bb.w);
      o[0] = (short)f2bf(a.x); o[1] = (short)f2bf(a.y);
      o[2] = (short)f2bf(a.z); o[3] = (short)f2bf(a.w);
      o[4] = (short)f2bf(bb.x); o[5] = (short)f2bf(bb.y);
      o[6] = (short)f2bf(bb.z); o[7] = (short)f2bf(bb.w);
      *(short8*)(wbf + (size_t)row * D_ + lane * 8) = o;
    }
  } else {
    const int row = (b - Q_ / 4) * 4 + wv;
    const float* pr = p + (size_t)row * D_ + lane * 8;
    float4 a = ((const float4*)pr)[0];
    float4 bb = ((const float4*)pr)[1];
    short8 o;
    o[0] = (short)f2bf(a.x); o[1] = (short)f2bf(a.y);
    o[2] = (short)f2bf(a.z); o[3] = (short)f2bf(a.w);
    o[4] = (short)f2bf(bb.x); o[5] = (short)f2bf(bb.y);
    o[6] = (short)f2bf(bb.z); o[7] = (short)f2bf(bb.w);
    *(short8*)(pbf + (size_t)row * D_ + lane * 8) = o;
  }
}

// grid (64, 8): x=split -> XCD=split%8, 2 blocks/CU, 512 blocks co-resident.
// Dual-GEMM, tile 128x128, 4 waves (2x2). Depth-2 pipelined K loop (BK=32,
// 3 LDS buffers, counted vmcnt). Epilogues identical to the verified baseline.
__global__ __launch_bounds__(256, 2) void fused_gemm_partial(
    const unsigned short* __restrict__ pbf,
    const unsigned short* __restrict__ qbf0,
    const unsigned short* __restrict__ wbf,
    const float* __restrict__ maskp,
    const int* __restrict__ label,
    char* __restrict__ ws) {
  __shared__ __align__(16) unsigned char smem[3 * SBUF3];   // 73728
  __shared__ float maskb[NT];
  __shared__ float zacc[MT][4];      // [row][wc*2+mat], accumulated across nt
  __shared__ int olist[MT];
  __shared__ int rowmap[MT];
  __shared__ int sh_ocount;

  const int tid = threadIdx.x;
  const int split = blockIdx.x;       // 0..63
  const int mblk = blockIdx.y;        // 0..7
  const int lane = tid & 63;
  const int wv = tid >> 6;
  const int wr = wv >> 1;
  const int wc = wv & 1;
  const int lr = lane & 15;
  const int lg = lane >> 4;

  if (tid == 0) sh_ocount = 0;
  if (tid < MT) {
    rowmap[tid] = -1;
    zacc[tid][0] = 0.0f; zacc[tid][1] = 0.0f;
    zacc[tid][2] = 0.0f; zacc[tid][3] = 0.0f;
  }
  __syncthreads();
  if (tid < MT) {
    if (label[mblk * MT + tid] == -1) {
      int k = atomicAdd(&sh_ocount, 1);
      olist[k] = tid;
    }
  }
  __syncthreads();
  const int noc = sh_ocount;
  if (tid < noc) rowmap[olist[tid]] = tid;
  __syncthreads();
  const int nchunks = (noc + 31) >> 5;

  // staging lane constants: lane covers local row (lane>>2) of a 16-row group,
  // source col16 = (l&3) ^ ((l>>2)&3) ^ ((l>>4)&1)  -> phys slot (l&3) holds
  // logical slot (phys ^ s(row)), s(row) = (row&3)^((row>>2)&1).
  const int srow4 = lane >> 2;
  const int sc16 = (lane & 3) ^ (srow4 & 3) ^ ((lane >> 4) & 1);
  const size_t g_lane_off = (size_t)srow4 * D_ + sc16 * 8;

  // compute-side swizzled slot offset (lane constant)
  const int xs = ((lg ^ (lr & 3) ^ ((lr >> 2) & 1))) * 16;

  // owner top-10 (only threads with tid&3==0 and pair<64 use it)
  float T[10];
#pragma unroll
  for (int i = 0; i < 10; ++i) T[i] = -1e30f;

  for (int nt = 0; nt < NTILES; ++nt) {
    const int nbase = split * NCHUNK + nt * NT;
    if (tid < NT) maskb[tid] = maskp[nbase + tid];
    __syncthreads();   // maskb ready; also fences smem reuse from prev nt scan

    // per-call B1 source select (per-lane row; mask==0 rows read qbf0 -> L2-hot)
    const unsigned short* b1p[2];
#pragma unroll
    for (int t = 0; t < 2; ++t)
      b1p[t] = (maskb[(wv * 2 + t) * 16 + srow4] != 0.0f) ? wbf : qbf0;

    f32x4 acc0[4][4], acc1[4][4];
#pragma unroll
    for (int i = 0; i < 4; ++i)
#pragma unroll
      for (int j = 0; j < 4; ++j) {
        f32x4 z = {0.0f, 0.0f, 0.0f, 0.0f};
        acc0[i][j] = z;
        acc1[i][j] = z;
      }

    // stage one 32-wide K-step into buffer buf: 6 async16 per thread
    auto stage = [&](int buf, int k2) {
      unsigned char* sb = smem + (size_t)buf * SBUF3;
      const size_t kcol = (size_t)k2 * 32;
#pragma unroll
      for (int t = 0; t < 2; ++t) {
        const int rb = (wv * 2 + t) * 16;
        async16(sb + (wv * 2 + t) * 1024,
                pbf + ((size_t)mblk * MT + rb) * D_ + kcol + g_lane_off);
        async16(sb + SB0_OFF3 + (wv * 2 + t) * 1024,
                qbf0 + ((size_t)nbase + rb) * D_ + kcol + g_lane_off);
        async16(sb + SB1_OFF3 + (wv * 2 + t) * 1024,
                b1p[t] + ((size_t)nbase + rb) * D_ + kcol + g_lane_off);
      }
    };

    stage(0, 0);
    stage(1, 1);

#pragma unroll
    for (int k2 = 0; k2 < KIT2; ++k2) {
      // wait for stage k2 (own 6 oldest); stage k2+1 (6) stays in flight
      if (k2 < KIT2 - 1)
        asm volatile("s_waitcnt vmcnt(6)" ::: "memory");
      else
        asm volatile("s_waitcnt vmcnt(0)" ::: "memory");
      asm volatile("s_barrier" ::: "memory");   // all waves' stage k2 landed
      if (k2 + 2 < KIT2) stage((k2 + 2) % 3, k2 + 2);

      const unsigned char* sb = smem + (size_t)(k2 % 3) * SBUF3;
      short8 af[4], bf0[4], bf1[4];
#pragma unroll
      for (int i = 0; i < 4; ++i)
        af[i] = *(const short8*)(sb + (wr * 64 + i * 16 + lr) * 64 + xs);
#pragma unroll
      for (int j = 0; j < 4; ++j)
        bf0[j] = *(const short8*)(sb + SB0_OFF3 + (wc * 64 + j * 16 + lr) * 64 + xs);
#pragma unroll
      for (int j = 0; j < 4; ++j)
        bf1[j] = *(const short8*)(sb + SB1_OFF3 + (wc * 64 + j * 16 + lr) * 64 + xs);
#pragma unroll
      for (int i = 0; i < 4; ++i)
#pragma unroll
        for (int j = 0; j < 4; ++j)
          acc0[i][j] = __builtin_amdgcn_mfma_f32_16x16x32_bf16(af[i], bf0[j], acc0[i][j], 0, 0, 0);
#pragma unroll
      for (int i = 0; i < 4; ++i)
#pragma unroll
        for (int j = 0; j < 4; ++j)
          acc1[i][j] = __builtin_amdgcn_mfma_f32_16x16x32_bf16(af[i], bf1[j], acc1[i][j], 0, 0, 0);
    }
    __syncthreads();   // all compute done before the scan aliases buf0

    // ---- Z epilogue: exps in regs, lr-shuffle reduce, LDS accumulate ----
#pragma unroll
    for (int i = 0; i < 4; ++i)
#pragma unroll
      for (int k = 0; k < 4; ++k) {
        float a0 = 0.0f, a1 = 0.0f;
#pragma unroll
        for (int j = 0; j < 4; ++j) {
          a0 += __builtin_amdgcn_exp2f(fmaf(acc0[i][j][k], C32, -C32));
          a1 += __builtin_amdgcn_exp2f(fmaf(acc1[i][j][k], C32, -C32));
        }
#pragma unroll
        for (int m = 1; m < 16; m <<= 1) {
          a0 += __shfl_xor(a0, m, 64);
          a1 += __shfl_xor(a1, m, 64);
        }
        if (lr == 0) {
          const int r = wr * 64 + i * 16 + lg * 4 + k;
          zacc[r][wc * 2 + 0] += a0;
          zacc[r][wc * 2 + 1] += a1;
        }
      }

    // ---- top-10 for outlier rows: LDS compact -> 4-thread scans -> merge ----
    for (int c = 0; c < nchunks; ++c) {
      unsigned short* cp = (unsigned short*)smem;   // aliases buf0 (16 KB)
#pragma unroll
      for (int i = 0; i < 4; ++i)
#pragma unroll
        for (int k = 0; k < 4; ++k) {
          const int r = wr * 64 + i * 16 + lg * 4 + k;
          const int o = rowmap[r];
          const int ol = o - c * 32;
          if (o >= 0 && ol >= 0 && ol < 32) {
#pragma unroll
            for (int j = 0; j < 4; ++j) {
              const int col = wc * 64 + j * 16 + lr;
              cp[ol * 128 + col] = f2bf(acc0[i][j][k]);
              cp[(32 + ol) * 128 + col] = f2bf(acc1[i][j][k]);
            }
          }
        }
      __syncthreads();

      {
        float tl[10];
#pragma unroll
        for (int r = 0; r < 10; ++r) tl[r] = -1e30f;
        const int pair = tid >> 2;      // 0..63: (orow, mat)
        const int q4 = tid & 3;
        const int orow = pair >> 1, mat = pair & 1;
        const int o = c * 32 + orow;
        if (o < noc) {
          const unsigned short* rp = cp + (mat * 32 + orow) * 128 + q4 * 32;
#pragma unroll
          for (int cc = 0; cc < 8; ++cc) {
            short4v v = *(const short4v*)(rp + cc * 4);
            TKA(bf2f(v.x), tl); TKA(bf2f(v.y), tl);
            TKA(bf2f(v.z), tl); TKA(bf2f(v.w), tl);
          }
          // merge across the 4 quarter-threads (same wave: xor 1 then 2)
          float ot[10];
#pragma unroll
          for (int r = 0; r < 10; ++r) ot[r] = __shfl_xor(tl[r], 1, 64);
#pragma unroll
          for (int r = 0; r < 10; ++r) TKA(ot[r], tl);
#pragma unroll
          for (int r = 0; r < 10; ++r) ot[r] = __shfl_xor(tl[r], 2, 64);
#pragma unroll
          for (int r = 0; r < 10; ++r) TKA(ot[r], tl);
          if (q4 == 0) {
            if (c == 0) {
#pragma unroll
              for (int r = 0; r < 10; ++r) TKA(tl[r], T);
            } else {
              // rare overflow path (noc > 32): RMW ws slot per nt
              float* slot = (float*)(ws + WS_TOPK) +
                  ((size_t)(mat * B_ + mblk * MT + olist[o]) * NSPLIT + split) * 10;
              if (nt == 0) {
#pragma unroll
                for (int r = 0; r < 10; ++r) slot[r] = tl[r];
              } else {
                float cur[10];
#pragma unroll
                for (int r = 0; r < 10; ++r) cur[r] = slot[r];
#pragma unroll
                for (int r = 0; r < 10; ++r) TKA(tl[r], cur);
#pragma unroll
                for (int r = 0; r < 10; ++r) slot[r] = cur[r];
              }
            }
          }
        }
      }
      __syncthreads();
    }
    // keep manual vmcnt accounting clean if the rare global RMW path ran
    if (nchunks > 1) asm volatile("s_waitcnt vmcnt(0)" ::: "memory");
  }

  // ---- block end: write Z partials and owner top-10 lists ----
  if (tid < MT) {
    float2* lseo = (float2*)(ws + WS_LSE);
    lseo[(size_t)(mblk * MT + tid) * NSPLIT + split] =
        make_float2(zacc[tid][0] + zacc[tid][2], zacc[tid][1] + zacc[tid][3]);
  }
  {
    const int pair = tid >> 2;
    const int q4 = tid & 3;
    const int orow = pair >> 1, mat = pair & 1;
    if (q4 == 0 && orow < noc && orow < 32) {
      float* slot = (float*)(ws + WS_TOPK) +
          ((size_t)(mat * B_ + mblk * MT + olist[orow]) * NSPLIT + split) * 10;
#pragma unroll
      for (int r = 0; r < 10; ++r) slot[r] = T[r];
    }
  }
}

// per-row: no global atomics — each row writes rowv[l*B+row]; reduce_final sums.
__global__ void finalize_rows(
    const float* __restrict__ p, const float* __restrict__ queue,
    const float* __restrict__ maskp, const int* __restrict__ label,
    char* __restrict__ ws, float* __restrict__ out) {
  const int row = blockIdx.x;
  const int l = threadIdx.x >> 6;     // 0: cos1 loss, 1: cos2 loss
  const int lane = threadIdx.x & 63;
  const int lab = label[row];
  float* rowv = (float*)(ws + WS_ROWV);

  if (lab != -1) {
    // ---- sum 64 split Z partials ----
    const float2* lsep = (const float2*)(ws + WS_LSE) + (size_t)row * NSPLIT;
    float2 zz = lsep[lane];
    float z = (l == 0) ? zz.x : zz.y;
#pragma unroll
    for (int o = 1; o < 64; o <<= 1) z += __shfl_xor(z, o, 64);

    // ---- exact fp32 gt dot(s) ----
    const float* prow = p + (size_t)row * D_;
    const float* q0r = queue + (size_t)lab * D_;
    const float* q1r = queue + ((size_t)Q_ + (size_t)lab) * D_;
    int c = lane * 8;
    float4 a0 = *(const float4*)(prow + c);
    float4 a1 = *(const float4*)(prow + c + 4);
    float4 b0 = *(const float4*)(q0r + c);
    float4 b1 = *(const float4*)(q0r + c + 4);
    float d0 = a0.x * b0.x + a0.y * b0.y + a0.z * b0.z + a0.w * b0.w
             + a1.x * b1.x + a1.y * b1.y + a1.z * b1.z + a1.w * b1.w;
    float d1 = 0.0f;
    if (l == 1) {
      float4 c0 = *(const float4*)(q1r + c);
      float4 c1 = *(const float4*)(q1r + c + 4);
      d1 = a0.x * c0.x + a0.y * c0.y + a0.z * c0.z + a0.w * c0.w
         + a1.x * c1.x + a1.y * c1.y + a1.z * c1.z + a1.w * c1.w;
    }
#pragma unroll
    for (int o = 1; o < 64; o <<= 1) {
      d0 += __shfl_xor(d0, o, 64);
      d1 += __shfl_xor(d1, o, 64);
    }
    float gt;
    if (l == 0) gt = d0;
    else { float m = maskp[lab]; gt = fmaf(m, d1 - d0, d0); }

    if (lane == 0) {
      float e1 = __builtin_amdgcn_exp2f(fmaf(gt, C32, -C32));
      float e2 = __builtin_amdgcn_exp2f(fmaf(gt - 0.4f, C32, -C32));
      float Zc = z - e1 + e2;
      float ce = 32.0f + __logf(Zc) - (gt - 0.4f) * SCALE32;
      rowv[l * B_ + row] = ce;
    }
  } else {
    // ---- merge 64 sorted top-10 lists: 10-round wave tournament ----
    const float* tp = (const float*)(ws + WS_TOPK) +
                      ((size_t)l * B_ + row) * NSPLIT * 10 + (size_t)lane * 10;
    float t0 = tp[0], t1 = tp[1], t2 = tp[2], t3 = tp[3], t4 = tp[4];
    float t5 = tp[5], t6 = tp[6], t7 = tp[7], t8 = tp[8], t9 = tp[9];
    float ssum = 0.0f;
#pragma unroll
    for (int r10 = 0; r10 < 10; ++r10) {
      float v = t0;
      int idx = lane;
#pragma unroll
      for (int o = 1; o < 64; o <<= 1) {
        float ov = __shfl_xor(v, o, 64);
        int oi = __shfl_xor(idx, o, 64);
        bool take = (ov > v) || (ov == v && oi < idx);
        v = take ? ov : v;
        idx = take ? oi : idx;
      }
      ssum += fmaxf(v, 0.0f);
      if (idx == lane) {
        t0 = t1; t1 = t2; t2 = t3; t3 = t4; t4 = t5;
        t5 = t6; t6 = t7; t7 = t8; t8 = t9; t9 = -1e30f;
      }
    }
    if (lane == 0) rowv[l * B_ + row] = ssum * 0.1f;
  }
}

// single-block deterministic reduction (no contended atomics)
__global__ void reduce_final(const int* __restrict__ label,
                             const char* __restrict__ ws,
                             float* __restrict__ out) {
  __shared__ float sce[4], sng[4];
  __shared__ int snp[4], snn[4];
  const int tid = threadIdx.x;        // 256 threads
  const float* rowv = (const float*)(ws + WS_ROWV);
  float ce = 0.0f, ng = 0.0f;
  int np = 0, nn = 0;
  for (int r = tid; r < B_; r += 256) {
    float v = rowv[r] + rowv[B_ + r];
    if (label[r] != -1) { ce += v; ++np; }
    else { ng += v; ++nn; }
  }
#pragma unroll
  for (int o = 1; o < 64; o <<= 1) {
    ce += __shfl_xor(ce, o, 64);
    ng += __shfl_xor(ng, o, 64);
    np += __shfl_xor(np, o, 64);
    nn += __shfl_xor(nn, o, 64);
  }
  const int wv = tid >> 6, lane = tid & 63;
  if (lane == 0) { sce[wv] = ce; sng[wv] = ng; snp[wv] = np; snn[wv] = nn; }
  __syncthreads();
  if (tid == 0) {
    float c = 0.0f, g = 0.0f; int p = 0, n = 0;
#pragma unroll
    for (int i = 0; i < 4; ++i) { c += sce[i]; g += sng[i]; p += snp[i]; n += snn[i]; }
    float loss = 0.0f;
    if (p > 0) loss += c / (float)p;
    if (n > 0) loss += g / (float)n;
    out[0] = loss;
  }
}

extern "C" void kernel_launch(void* const* d_in, const int* in_sizes, int n_in,
                              void* d_out, int out_size, void* d_ws, size_t ws_size,
                              hipStream_t stream) {
  const float* p     = (const float*)d_in[0];
  const float* queue = (const float*)d_in[1];
  const float* maskp = (const float*)d_in[2];
  const int*   label = (const int*)d_in[3];
  float* out = (float*)d_out;
  char* ws = (char*)d_ws;

  unsigned short* pbf  = (unsigned short*)(ws + WS_PBF);
  unsigned short* qbf0 = (unsigned short*)(ws + WS_QBF0);
  unsigned short* wbf  = (unsigned short*)(ws + WS_WBF);

  cvt_all<<<Q_ / 4 + B_ / 4, 256, 0, stream>>>(queue, p, maskp, qbf0, wbf, pbf);

  dim3 g1(NSPLIT, B_ / MT);   // (64, 8): x=split -> XCD=split%8
  fused_gemm_partial<<<g1, 256, 0, stream>>>(pbf, qbf0, wbf, maskp, label, ws);
  finalize_rows<<<B_, 128, 0, stream>>>(p, queue, maskp, label, ws, out);
  reduce_final<<<1, 256, 0, stream>>>(label, ws, out);
}